// Round 9
// baseline (589.778 us; speedup 1.0000x reference)
//
#include <hip/hip_runtime.h>
#include <type_traits>

typedef __attribute__((ext_vector_type(8))) short  vshort8;
typedef __attribute__((ext_vector_type(8))) __bf16 vbf16x8;
typedef __attribute__((ext_vector_type(4))) float  vfloat4;

__device__ __forceinline__ float bf2f(unsigned short h) {
    return __uint_as_float(((unsigned int)h) << 16);
}
__device__ __forceinline__ unsigned short f2bf(float f) {
    unsigned int u = __float_as_uint(f);
    unsigned int r = (u + 0x7FFFu + ((u >> 16) & 1u)) >> 16;
    return (unsigned short)r;
}
__device__ __forceinline__ vshort8 cvt8s(const float* p, float s) {
    float4 a = *(const float4*)p;
    float4 b = *(const float4*)(p + 4);
    vshort8 r;
    r[0] = (short)f2bf(a.x * s); r[1] = (short)f2bf(a.y * s);
    r[2] = (short)f2bf(a.z * s); r[3] = (short)f2bf(a.w * s);
    r[4] = (short)f2bf(b.x * s); r[5] = (short)f2bf(b.y * s);
    r[6] = (short)f2bf(b.z * s); r[7] = (short)f2bf(b.w * s);
    return r;
}
__device__ __forceinline__ vshort8 cvt8(const float* p) { return cvt8s(p, 1.0f); }
// async global->LDS, 16B per lane; LDS base must be wave-uniform.
__device__ __forceinline__ void gload16(const void* g, void* lds) {
    __builtin_amdgcn_global_load_lds(
        (const __attribute__((address_space(1))) unsigned int*)g,
        (__attribute__((address_space(3))) unsigned int*)lds, 16, 0, 0);
}

// ---------------------------------------------------------------------------
// fp32 -> bf16 bulk convert (hidden states)
// ---------------------------------------------------------------------------
__global__ __launch_bounds__(256) void hconv_kernel(
    const float* __restrict__ in, unsigned short* __restrict__ out, int n8)
{
    int i = blockIdx.x * 256 + threadIdx.x;
    if (i < n8) *(vshort8*)(out + (size_t)i * 8) = cvt8(in + (size_t)i * 8);
}

// ---------------------------------------------------------------------------
// Weight transpose+convert: W[K][N] fp32 -> Wt[rowoff+n][K] bf16, times scale.
// ---------------------------------------------------------------------------
__global__ __launch_bounds__(256) void wtrans_kernel(
    const float* __restrict__ W, unsigned short* __restrict__ Wt,
    int ldw, int ldt, int rowoff, float scale)
{
    __shared__ __align__(16) unsigned short Ls[64][72];
    const int t = threadIdx.x;
    const int n0 = blockIdx.x * 64, k0 = blockIdx.y * 64;
    const int rr = t >> 2, cc = t & 3;   // rr: 0..63, cc: 0..3

    const float* src = W + (size_t)(k0 + rr) * ldw + n0 + cc * 16;
    *(vshort8*)&Ls[rr][cc * 16]     = cvt8s(src, scale);
    *(vshort8*)&Ls[rr][cc * 16 + 8] = cvt8s(src + 8, scale);
    __syncthreads();

    unsigned short* dst = Wt + (size_t)(rowoff + n0 + rr) * ldt + k0 + cc * 16;
    vshort8 v0, v1;
    #pragma unroll
    for (int j = 0; j < 8; ++j) {
        v0[j] = (short)Ls[cc * 16 + j][rr];
        v1[j] = (short)Ls[cc * 16 + 8 + j][rr];
    }
    *(vshort8*)dst = v0;
    *(vshort8*)(dst + 8) = v1;
}

// ---------------------------------------------------------------------------
// m97-style GEMM, BK=64 (round-6 win). LDS LINEAR [128][64] for
// global_load_lds; bank wrap broken by row-parity half-swap on BOTH sides
// (rule #21): global SOURCE column XORs its 32-col half with (row&1);
// ds_read applies the same XOR (kk ^ (lm&1)). 32KB LDS. K % 64 == 0.
// ---------------------------------------------------------------------------
template<typename CT>
__global__ __launch_bounds__(256) void gemm_tt(
    const unsigned short* __restrict__ A, const unsigned short* __restrict__ Bt,
    CT* __restrict__ C0, CT* __restrict__ C1,
    int K, int N, int nsplit, int ldc0, int ldc1)
{
    __shared__ __align__(16) unsigned short As[128 * 64];
    __shared__ __align__(16) unsigned short Bs[128 * 64];

    const int t = threadIdx.x, lane = t & 63, w = t >> 6;
    const int lm = lane & 15, quad = lane >> 4;
    const int wm = w >> 1, wn = w & 1;
    const int m0 = blockIdx.y * 128, n0 = blockIdx.x * 128;
    const int srow = lane >> 3, sseg = lane & 7;
    const int scol = (((sseg >> 2) ^ (srow & 1)) << 5) + (sseg & 3) * 8;

    vfloat4 acc[4][4] = {};

    for (int k0 = 0; k0 < K; k0 += 64) {
        #pragma unroll
        for (int j = 0; j < 4; ++j) {
            int r = w * 32 + j * 8 + srow;
            gload16(A  + (size_t)(m0 + r) * K + k0 + scol, &As[(w * 32 + j * 8) * 64]);
            gload16(Bt + (size_t)(n0 + r) * K + k0 + scol, &Bs[(w * 32 + j * 8) * 64]);
        }
        __syncthreads();

        #pragma unroll
        for (int kk = 0; kk < 2; ++kk) {
            const int xo = ((kk ^ (lm & 1)) << 5) + quad * 8;  // de-swizzle
            vbf16x8 af[4], bw[4];
            #pragma unroll
            for (int i = 0; i < 4; ++i) {
                af[i] = *(const vbf16x8*)&As[(wm * 64 + i * 16 + lm) * 64 + xo];
                bw[i] = *(const vbf16x8*)&Bs[(wn * 64 + i * 16 + lm) * 64 + xo];
            }
            #pragma unroll
            for (int mi = 0; mi < 4; ++mi)
                #pragma unroll
                for (int ni = 0; ni < 4; ++ni)
                    acc[mi][ni] = __builtin_amdgcn_mfma_f32_16x16x32_bf16(af[mi], bw[ni], acc[mi][ni], 0, 0, 0);
        }
        __syncthreads();
    }

    #pragma unroll
    for (int mi = 0; mi < 4; ++mi) {
        #pragma unroll
        for (int ni = 0; ni < 4; ++ni) {
            int col = n0 + wn * 64 + ni * 16 + lm;
            if (col >= N) continue;
            #pragma unroll
            for (int r = 0; r < 4; ++r) {
                int row = m0 + wm * 64 + mi * 16 + quad * 4 + r;
                float v = acc[mi][ni][r];
                if (col < nsplit) {
                    if constexpr (std::is_same_v<CT, float>) C0[(size_t)row * ldc0 + col] = v;
                    else C0[(size_t)row * ldc0 + col] = f2bf(v);
                } else {
                    if constexpr (std::is_same_v<CT, float>) C1[(size_t)row * ldc1 + col - nsplit] = v;
                    else C1[(size_t)row * ldc1 + col - nsplit] = f2bf(v);
                }
            }
        }
    }
}

// ---------------------------------------------------------------------------
// G4 GEMM with scatter epilogue (BK=32; K=512 short loop).
//   even blockIdx.x: d < 128 -> Kn[row][h*128+d] (coalesced)
//   odd  blockIdx.x: d >= 128 -> VT via LDS transpose, coalesced 64B runs
// ---------------------------------------------------------------------------
__global__ __launch_bounds__(256) void gemm_kv(
    const unsigned short* __restrict__ A, const unsigned short* __restrict__ Bt,
    unsigned short* __restrict__ Kn, unsigned short* __restrict__ VT, int K)
{
    __shared__ __align__(16) unsigned short As[128 * 32];
    __shared__ __align__(16) unsigned short Bs[128 * 32];
    __shared__ __align__(16) unsigned short Ts[64][136];   // transpose buffer

    const int t = threadIdx.x, lane = t & 63, w = t >> 6;
    const int lm = lane & 15, quad = lane >> 4;
    const int wm = w >> 1, wn = w & 1;
    const int m0 = blockIdx.y * 128, n0 = blockIdx.x * 128;
    const int srow = lane >> 2, sseg = lane & 3;

    vfloat4 acc[4][4] = {};

    for (int k0 = 0; k0 < K; k0 += 32) {
        #pragma unroll
        for (int j = 0; j < 2; ++j) {
            int r = w * 32 + j * 16 + srow;
            gload16(A  + (size_t)(m0 + r) * K + k0 + sseg * 8, &As[(w * 2 + j) * 512]);
            gload16(Bt + (size_t)(n0 + r) * K + k0 + sseg * 8, &Bs[(w * 2 + j) * 512]);
        }
        __syncthreads();

        vbf16x8 af[4], bw[4];
        #pragma unroll
        for (int i = 0; i < 4; ++i) {
            af[i] = *(const vbf16x8*)&As[(wm * 64 + i * 16 + lm) * 32 + quad * 8];
            bw[i] = *(const vbf16x8*)&Bs[(wn * 64 + i * 16 + lm) * 32 + quad * 8];
        }
        #pragma unroll
        for (int mi = 0; mi < 4; ++mi)
            #pragma unroll
            for (int ni = 0; ni < 4; ++ni)
                acc[mi][ni] = __builtin_amdgcn_mfma_f32_16x16x32_bf16(af[mi], bw[ni], acc[mi][ni], 0, 0, 0);
        __syncthreads();
    }

    if (!(blockIdx.x & 1)) {
        const int hh = blockIdx.x >> 1;
        #pragma unroll
        for (int mi = 0; mi < 4; ++mi) {
            #pragma unroll
            for (int ni = 0; ni < 4; ++ni) {
                int d = wn * 64 + ni * 16 + lm;
                #pragma unroll
                for (int r = 0; r < 4; ++r) {
                    int row = m0 + wm * 64 + mi * 16 + quad * 4 + r;
                    Kn[(size_t)row * 2048 + hh * 128 + d] = f2bf(acc[mi][ni][r]);
                }
            }
        }
    } else {
        const int hh   = blockIdx.x >> 1;       // head
        const int bb   = m0 >> 11;              // batch
        const int tok0 = m0 & 2047;             // first token of tile
        #pragma unroll
        for (int half = 0; half < 2; ++half) {
            if (wn == half) {
                #pragma unroll
                for (int mi = 0; mi < 4; ++mi) {
                    #pragma unroll
                    for (int ni = 0; ni < 4; ++ni) {
                        int ln = ni * 16 + lm;                    // 0..63
                        int rt = wm * 64 + mi * 16 + quad * 4;    // 0..124
                        #pragma unroll
                        for (int r = 0; r < 4; ++r)
                            Ts[ln][rt + r] = f2bf(acc[mi][ni][r]);
                    }
                }
            }
            __syncthreads();
            {
                int tr = t >> 2, seg = t & 3;    // 64 rows x 4 segments
                int dv = half * 64 + tr;
                unsigned short* dst =
                    VT + ((size_t)(bb * 16 + hh) * 128 + dv) * 2048 + tok0 + seg * 32;
                const unsigned short* srcp = &Ts[tr][seg * 32];
                #pragma unroll
                for (int j = 0; j < 4; ++j)
                    *(vshort8*)(dst + j * 8) = *(const vshort8*)(srcp + j * 8);
            }
            __syncthreads();
        }
    }
}

// ---------------------------------------------------------------------------
// RMSNorm (bf16 activations, fp32 weight)
// ---------------------------------------------------------------------------
__global__ __launch_bounds__(256) void rmsnorm_kernel(
    const unsigned short* __restrict__ in, const float* __restrict__ wgt,
    unsigned short* __restrict__ out, int width, int ld_in, int ld_out)
{
    const int row = blockIdx.x;
    const int t = threadIdx.x;
    const unsigned short* x = in + (size_t)row * ld_in;

    float ss = 0.f;
    for (int i = t; i < width; i += 256) { float v = bf2f(x[i]); ss += v * v; }
    #pragma unroll
    for (int off = 32; off > 0; off >>= 1) ss += __shfl_down(ss, off, 64);

    __shared__ float red[4];
    __shared__ float rr;
    if ((t & 63) == 0) red[t >> 6] = ss;
    __syncthreads();
    if (t == 0) rr = rsqrtf((red[0] + red[1] + red[2] + red[3]) / (float)width + 1e-6f);
    __syncthreads();
    float r = rr;
    unsigned short* o = out + (size_t)row * ld_out;
    for (int i = t; i < width; i += 256) o[i] = f2bf(bf2f(x[i]) * r * wgt[i]);
}

// ---------------------------------------------------------------------------
// RoPE on q_pe, PE dims only (SCALE pre-folded into w_qb at wtrans time).
// ---------------------------------------------------------------------------
__global__ __launch_bounds__(256) void rope_q_kernel(
    unsigned short* __restrict__ q, const float* __restrict__ cosb,
    const float* __restrict__ sinb)
{
    const int row = blockIdx.x;
    const int s = row & 2047;
    const int t = threadIdx.x;
    unsigned short* qr = q + (size_t)row * 3072;
    const int i = t & 31;                 // pair index, same for both c-iters
    const float cs = cosb[s * 64 + i];
    const float sn = sinb[s * 64 + i];

    #pragma unroll
    for (int c = t; c < 512; c += 256) {
        int h = c >> 5;
        unsigned short* p = qr + h * 192 + 128 + i;
        float x = bf2f(p[0]);
        float y = bf2f(p[32]);
        p[0]  = f2bf(x * cs - y * sn);
        p[32] = f2bf(y * cs + x * sn);
    }
}

// ---------------------------------------------------------------------------
// RoPE on k_pe: ckv[:, 512:576] -> kpe[token][64]
// ---------------------------------------------------------------------------
__global__ __launch_bounds__(64) void rope_k_kernel(
    const unsigned short* __restrict__ ckv, const float* __restrict__ cosb,
    const float* __restrict__ sinb, unsigned short* __restrict__ kpe)
{
    const int row = blockIdx.x;
    const int s = row & 2047;
    const int t = threadIdx.x;
    if (t < 32) {
        float cs = cosb[s * 64 + t];
        float sn = sinb[s * 64 + t];
        float x = bf2f(ckv[(size_t)row * 576 + 512 + t]);
        float y = bf2f(ckv[(size_t)row * 576 + 544 + t]);
        kpe[(size_t)row * 64 + t]      = f2bf(x * cs - y * sn);
        kpe[(size_t)row * 64 + 32 + t] = f2bf(y * cs + x * sn);
    }
}

// ---------------------------------------------------------------------------
// Causal flash attention, round-8 restructure (resubmitted after infra fail):
//  (a) V staging DROPPED (m169 precedent): PV reads VT directly from global.
//      V slice is L2-resident after round-7's XCD co-location; each tile was
//      used once per iter, so staging was pure copy overhead. Also removes
//      the post-PV barrier (it only protected Vs/Ks overwrite; Ps is
//      wave-private) -> 2 barriers/iter instead of 3.
//  (b) LDS 53248 -> 34816 B (Ks+Ps only) -> 4 blocks/CU capacity.
//  (c) De-paired 1024-block grid = exactly 256 CUs x 4 resident blocks (no
//      queuing -> no round-4 stragglers). qt permutation: the 4 blocks that
//      land on one CU under RR fill (bids = c mod 256) get qt-set
//      {a, 31-a, 8+a, 23-a} = 66 k-iters constant. bid&31 = (h,b) group
//      preserves round-7's proven XCD/L2 mapping (FETCH 263->36 MB).
//  VGPR must stay <128 (rounds 1-2 cliff lesson) — no other state added.
// ---------------------------------------------------------------------------
__global__ __launch_bounds__(256) void flash_kernel(
    const unsigned short* __restrict__ Q, const unsigned short* __restrict__ Kn,
    const unsigned short* __restrict__ KPE, const unsigned short* __restrict__ VT,
    unsigned short* __restrict__ O)
{
    __shared__ __align__(16) unsigned short Ks[64][200];
    __shared__ __align__(16) unsigned short Ps[4][16][72];

    const int t    = threadIdx.x;
    const int lane = t & 63;
    const int w    = t >> 6;
    const int lm   = lane & 15, quad = lane >> 4;
    const int bid = blockIdx.x;
    const int g = bid & 31;          // (h,b) group: same-g -> same XCD (r7)
    const int s = bid >> 5;          // q-slot 0..31
    const int v = s >> 3, u = s & 7;
    const int qt = (v == 0) ? u : (v == 1) ? 31 - u : (v == 2) ? 8 + u : 23 - u;
    const int h = g & 15, b = g >> 4;
    const int tb = b * 2048;
    const unsigned short* VTbh = VT + (size_t)(b * 16 + h) * 128 * 2048;
    // per-lane V base: PV lane (lm,quad) reads VT[vt*16+lm][kb + kc*32 + quad*8]
    const unsigned short* Vlane = VTbh + (size_t)lm * 2048 + quad * 8;

    const int qtok = tb + qt * 64 + w * 16 + lm;
    vbf16x8 aq[6];
    #pragma unroll
    for (int ch = 0; ch < 6; ++ch)
        aq[ch] = *(const vbf16x8*)(Q + (size_t)qtok * 3072 + h * 192 + ch * 32 + quad * 8);

    vfloat4 acc_o[8];
    #pragma unroll
    for (int i = 0; i < 8; ++i) acc_o[i] = (vfloat4){0, 0, 0, 0};
    float mrow[4], lrow[4];
    #pragma unroll
    for (int r = 0; r < 4; ++r) { mrow[r] = -3.0e38f; lrow[r] = 0.f; }

    for (int kt = 0; kt <= qt; ++kt) {
        const int kb = kt * 64;
        // stage K_nope (contiguous 128-short rows of Kn)
        #pragma unroll
        for (int it = 0; it < 4; ++it) {
            int idx = t + it * 256;
            int row = idx >> 4, sg = idx & 15;
            *(vshort8*)&Ks[row][sg * 8] =
                *(const vshort8*)(Kn + (size_t)(tb + kb + row) * 2048 + h * 128 + sg * 8);
        }
        // stage K_pe
        #pragma unroll
        for (int it = 0; it < 2; ++it) {
            int idx = t + it * 256;
            int row = idx >> 3, sg = idx & 7;
            *(vshort8*)&Ks[row][128 + sg * 8] =
                *(const vshort8*)(KPE + (size_t)(tb + kb + row) * 64 + sg * 8);
        }
        __syncthreads();

        // S = Q K^T (wave strip: 16 q x 64 k)
        vfloat4 accs[4];
        #pragma unroll
        for (int ni = 0; ni < 4; ++ni) accs[ni] = (vfloat4){0, 0, 0, 0};
        #pragma unroll
        for (int ni = 0; ni < 4; ++ni) {
            #pragma unroll
            for (int ch = 0; ch < 6; ++ch) {
                vbf16x8 bk = *(const vbf16x8*)&Ks[ni * 16 + lm][ch * 32 + quad * 8];
                accs[ni] = __builtin_amdgcn_mfma_f32_16x16x32_bf16(aq[ch], bk, accs[ni], 0, 0, 0);
            }
        }

        // causal mask
        const int qrow = qt * 64 + w * 16 + quad * 4;
        #pragma unroll
        for (int ni = 0; ni < 4; ++ni) {
            int ki = kb + ni * 16 + lm;
            #pragma unroll
            for (int r = 0; r < 4; ++r)
                if (ki > qrow + r) accs[ni][r] = -3.0e38f;
        }

        // online softmax
        #pragma unroll
        for (int r = 0; r < 4; ++r) {
            float mx = fmaxf(fmaxf(accs[0][r], accs[1][r]), fmaxf(accs[2][r], accs[3][r]));
            #pragma unroll
            for (int off = 1; off < 16; off <<= 1) mx = fmaxf(mx, __shfl_xor(mx, off, 64));
            float mnew  = fmaxf(mrow[r], mx);
            float alpha = __expf(mrow[r] - mnew);
            float sum = 0.f;
            #pragma unroll
            for (int ni = 0; ni < 4; ++ni) {
                float pv = __expf(accs[ni][r] - mnew);
                accs[ni][r] = pv;
                sum += pv;
            }
            #pragma unroll
            for (int off = 1; off < 16; off <<= 1) sum += __shfl_xor(sum, off, 64);
            lrow[r] = lrow[r] * alpha + sum;
            mrow[r] = mnew;
            #pragma unroll
            for (int vt = 0; vt < 8; ++vt) acc_o[vt][r] *= alpha;
        }

        // P: C-layout -> LDS -> A-layout (Ps is wave-private)
        #pragma unroll
        for (int ni = 0; ni < 4; ++ni)
            #pragma unroll
            for (int r = 0; r < 4; ++r)
                Ps[w][quad * 4 + r][ni * 16 + lm] = f2bf(accs[ni][r]);
        // barrier: all waves done READING Ks (QK) before next-iter staging
        // overwrites it. Ps is wave-private; V comes from global.
        __syncthreads();

        // O += P V  (V direct from global; L2-resident slice)
        #pragma unroll
        for (int kc = 0; kc < 2; ++kc) {
            vbf16x8 ap = *(const vbf16x8*)&Ps[w][lm][kc * 32 + quad * 8];
            #pragma unroll
            for (int vt = 0; vt < 8; ++vt) {
                vbf16x8 bv = *(const vbf16x8*)(Vlane + (size_t)(vt * 16) * 2048 + kb + kc * 32);
                acc_o[vt] = __builtin_amdgcn_mfma_f32_16x16x32_bf16(ap, bv, acc_o[vt], 0, 0, 0);
            }
        }
        // no post-PV barrier needed: next stage writes Ks only, and every
        // wave's QK-read of Ks for this iter happened before the barrier above.
    }

    #pragma unroll
    for (int r = 0; r < 4; ++r) {
        float inv = 1.f / lrow[r];
        int tok = tb + qt * 64 + w * 16 + quad * 4 + r;
        #pragma unroll
        for (int vt = 0; vt < 8; ++vt)
            O[(size_t)tok * 2048 + h * 128 + vt * 16 + lm] = f2bf(acc_o[vt][r] * inv);
    }
}

// ---------------------------------------------------------------------------
extern "C" void kernel_launch(void* const* d_in, const int* in_sizes, int n_in,
                              void* d_out, int out_size, void* d_ws, size_t ws_size,
                              hipStream_t stream) {
    const float* hidden = (const float*)d_in[0];
    // d_in[1] = attention_mask (pure causal; applied analytically)
    const float* cosb   = (const float*)d_in[2];
    const float* sinb   = (const float*)d_in[3];
    const float* w_qa   = (const float*)d_in[4];
    const float* qa_ln  = (const float*)d_in[5];
    const float* w_qb   = (const float*)d_in[6];
    const float* w_kva  = (const float*)d_in[7];
    const float* kva_ln = (const float*)d_in[8];
    const float* w_kvb  = (const float*)d_in[9];
    const float* w_o    = (const float*)d_in[10];
    float* out = (float*)d_out;
    const float SCALE = 0.07216878364870323f;  // 192^-0.5, folded into w_qb

    // Workspace overlays (ushort units). Peak 47,185,920 u = 94.4 MB
    unsigned short* ws   = (unsigned short*)d_ws;
    unsigned short* hb   = ws;                  // 4096x2048 [hconv..G1G2]
    unsigned short* Kn   = ws;                  // 4096x2048 [G4..flash]
    unsigned short* wt12 = ws + 8388608;        // 2176x2048 [prep..G1G2]
    unsigned short* VT   = ws + 8388608;        // 32x128x2048 [G4..flash]
    unsigned short* ot   = ws + 8388608;        // 2048x2048 [post-flash..G5]
    unsigned short* qbuf = ws + 16777216;       // 4096x3072
    unsigned short* q_a  = ws + 29360128;       // 4096x1536 [G1G2..G3]
    unsigned short* ckv  = ws + 35651584;       // 4096x576  [G1G2..rope_k]
    unsigned short* aout = ws + 29360128;       // 4096x2048 [flash..G5]
    unsigned short* qbt  = ws + 38010880;       // 3072x1536
    unsigned short* kvbt = ws + 42729472;       // 4096x512
    unsigned short* kvn  = ws + 44826624;       // 4096x512
    unsigned short* kpe  = ws + 46923776;       // 4096x64   -> end 47185920

    dim3 blk(256);

    // Prepass: hidden -> bf16; weights -> bf16 transposed (N-major rows, K cols)
    hconv_kernel<<<4096, blk, 0, stream>>>(hidden, hb, 1048576);
    wtrans_kernel<<<dim3(24, 32), blk, 0, stream>>>(w_qa,  wt12, 1536, 2048, 0,    1.0f);
    wtrans_kernel<<<dim3( 9, 32), blk, 0, stream>>>(w_kva, wt12,  576, 2048, 1536, 1.0f);
    wtrans_kernel<<<dim3(48, 24), blk, 0, stream>>>(w_qb,  qbt,  3072, 1536, 0,    SCALE);
    wtrans_kernel<<<dim3(64,  8), blk, 0, stream>>>(w_kvb, kvbt, 4096,  512, 0,    1.0f);

    // G1+G2 fused: [q_a | ckv] = hidden @ [w_qa | w_kva]  (N=2112, split 1536)
    gemm_tt<unsigned short><<<dim3(17, 32), blk, 0, stream>>>(
        hb, wt12, q_a, ckv, 2048, 2112, 1536, 1536, 576);

    rmsnorm_kernel<<<4096, blk, 0, stream>>>(q_a, qa_ln, q_a, 1536, 1536, 1536);
    rmsnorm_kernel<<<4096, blk, 0, stream>>>(ckv, kva_ln, kvn, 512, 576, 512);
    rope_k_kernel<<<4096, dim3(64), 0, stream>>>(ckv, cosb, sinb, kpe);

    // G3: qbuf = q_a_norm @ w_qb (pre-scaled); then rope (PE dims only)
    gemm_tt<unsigned short><<<dim3(24, 32), blk, 0, stream>>>(
        q_a, qbt, qbuf, qbuf, 1536, 3072, 3072, 3072, 3072);
    rope_q_kernel<<<4096, blk, 0, stream>>>(qbuf, cosb, sinb);

    // G4: [Kn | VT] = kv_norm @ w_kvb  (split epilogue, coalesced VT)
    gemm_kv<<<dim3(32, 32), blk, 0, stream>>>(kvn, kvbt, Kn, VT, 512);

    // attention: 1024 blocks (one qt each), CU-balanced perm, XCD-co-located
    flash_kernel<<<dim3(1024), blk, 0, stream>>>(qbuf, Kn, kpe, VT, aout);

    // w_o transpose (deferred: reuses VT region after flash)
    wtrans_kernel<<<dim3(32, 32), blk, 0, stream>>>(w_o, ot, 2048, 2048, 0, 1.0f);

    // G5: out = attn_out @ w_o (fp32 output)
    gemm_tt<float><<<dim3(16, 32), blk, 0, stream>>>(
        aout, ot, out, out, 2048, 2048, 2048, 2048, 2048);
}

// Round 11
// 554.827 us; speedup vs baseline: 1.0630x; 1.0630x over previous
//
#include <hip/hip_runtime.h>
#include <type_traits>

typedef __attribute__((ext_vector_type(8))) short  vshort8;
typedef __attribute__((ext_vector_type(8))) __bf16 vbf16x8;
typedef __attribute__((ext_vector_type(4))) float  vfloat4;

__device__ __forceinline__ float bf2f(unsigned short h) {
    return __uint_as_float(((unsigned int)h) << 16);
}
__device__ __forceinline__ unsigned short f2bf(float f) {
    unsigned int u = __float_as_uint(f);
    unsigned int r = (u + 0x7FFFu + ((u >> 16) & 1u)) >> 16;
    return (unsigned short)r;
}
__device__ __forceinline__ vshort8 cvt8s(const float* p, float s) {
    float4 a = *(const float4*)p;
    float4 b = *(const float4*)(p + 4);
    vshort8 r;
    r[0] = (short)f2bf(a.x * s); r[1] = (short)f2bf(a.y * s);
    r[2] = (short)f2bf(a.z * s); r[3] = (short)f2bf(a.w * s);
    r[4] = (short)f2bf(b.x * s); r[5] = (short)f2bf(b.y * s);
    r[6] = (short)f2bf(b.z * s); r[7] = (short)f2bf(b.w * s);
    return r;
}
__device__ __forceinline__ vshort8 cvt8(const float* p) { return cvt8s(p, 1.0f); }
// async global->LDS, 16B per lane; LDS base must be wave-uniform.
__device__ __forceinline__ void gload16(const void* g, void* lds) {
    __builtin_amdgcn_global_load_lds(
        (const __attribute__((address_space(1))) unsigned int*)g,
        (__attribute__((address_space(3))) unsigned int*)lds, 16, 0, 0);
}

// ---------------------------------------------------------------------------
// fp32 -> bf16 bulk convert (hidden states)
// ---------------------------------------------------------------------------
__global__ __launch_bounds__(256) void hconv_kernel(
    const float* __restrict__ in, unsigned short* __restrict__ out, int n8)
{
    int i = blockIdx.x * 256 + threadIdx.x;
    if (i < n8) *(vshort8*)(out + (size_t)i * 8) = cvt8(in + (size_t)i * 8);
}

// ---------------------------------------------------------------------------
// Weight transpose+convert: W[K][N] fp32 -> Wt[rowoff+n][K] bf16, times scale.
// ---------------------------------------------------------------------------
__global__ __launch_bounds__(256) void wtrans_kernel(
    const float* __restrict__ W, unsigned short* __restrict__ Wt,
    int ldw, int ldt, int rowoff, float scale)
{
    __shared__ __align__(16) unsigned short Ls[64][72];
    const int t = threadIdx.x;
    const int n0 = blockIdx.x * 64, k0 = blockIdx.y * 64;
    const int rr = t >> 2, cc = t & 3;   // rr: 0..63, cc: 0..3

    const float* src = W + (size_t)(k0 + rr) * ldw + n0 + cc * 16;
    *(vshort8*)&Ls[rr][cc * 16]     = cvt8s(src, scale);
    *(vshort8*)&Ls[rr][cc * 16 + 8] = cvt8s(src + 8, scale);
    __syncthreads();

    unsigned short* dst = Wt + (size_t)(rowoff + n0 + rr) * ldt + k0 + cc * 16;
    vshort8 v0, v1;
    #pragma unroll
    for (int j = 0; j < 8; ++j) {
        v0[j] = (short)Ls[cc * 16 + j][rr];
        v1[j] = (short)Ls[cc * 16 + 8 + j][rr];
    }
    *(vshort8*)dst = v0;
    *(vshort8*)(dst + 8) = v1;
}

// ---------------------------------------------------------------------------
// m97-style GEMM, BK=64 (round-6 win). LDS LINEAR [128][64] for
// global_load_lds; bank wrap broken by row-parity half-swap on BOTH sides
// (rule #21): global SOURCE column XORs its 32-col half with (row&1);
// ds_read applies the same XOR (kk ^ (lm&1)). 32KB LDS. K % 64 == 0.
// ---------------------------------------------------------------------------
template<typename CT>
__global__ __launch_bounds__(256) void gemm_tt(
    const unsigned short* __restrict__ A, const unsigned short* __restrict__ Bt,
    CT* __restrict__ C0, CT* __restrict__ C1,
    int K, int N, int nsplit, int ldc0, int ldc1)
{
    __shared__ __align__(16) unsigned short As[128 * 64];
    __shared__ __align__(16) unsigned short Bs[128 * 64];

    const int t = threadIdx.x, lane = t & 63, w = t >> 6;
    const int lm = lane & 15, quad = lane >> 4;
    const int wm = w >> 1, wn = w & 1;
    const int m0 = blockIdx.y * 128, n0 = blockIdx.x * 128;
    const int srow = lane >> 3, sseg = lane & 7;
    const int scol = (((sseg >> 2) ^ (srow & 1)) << 5) + (sseg & 3) * 8;

    vfloat4 acc[4][4] = {};

    for (int k0 = 0; k0 < K; k0 += 64) {
        #pragma unroll
        for (int j = 0; j < 4; ++j) {
            int r = w * 32 + j * 8 + srow;
            gload16(A  + (size_t)(m0 + r) * K + k0 + scol, &As[(w * 32 + j * 8) * 64]);
            gload16(Bt + (size_t)(n0 + r) * K + k0 + scol, &Bs[(w * 32 + j * 8) * 64]);
        }
        __syncthreads();

        #pragma unroll
        for (int kk = 0; kk < 2; ++kk) {
            const int xo = ((kk ^ (lm & 1)) << 5) + quad * 8;  // de-swizzle
            vbf16x8 af[4], bw[4];
            #pragma unroll
            for (int i = 0; i < 4; ++i) {
                af[i] = *(const vbf16x8*)&As[(wm * 64 + i * 16 + lm) * 64 + xo];
                bw[i] = *(const vbf16x8*)&Bs[(wn * 64 + i * 16 + lm) * 64 + xo];
            }
            #pragma unroll
            for (int mi = 0; mi < 4; ++mi)
                #pragma unroll
                for (int ni = 0; ni < 4; ++ni)
                    acc[mi][ni] = __builtin_amdgcn_mfma_f32_16x16x32_bf16(af[mi], bw[ni], acc[mi][ni], 0, 0, 0);
        }
        __syncthreads();
    }

    #pragma unroll
    for (int mi = 0; mi < 4; ++mi) {
        #pragma unroll
        for (int ni = 0; ni < 4; ++ni) {
            int col = n0 + wn * 64 + ni * 16 + lm;
            if (col >= N) continue;
            #pragma unroll
            for (int r = 0; r < 4; ++r) {
                int row = m0 + wm * 64 + mi * 16 + quad * 4 + r;
                float v = acc[mi][ni][r];
                if (col < nsplit) {
                    if constexpr (std::is_same_v<CT, float>) C0[(size_t)row * ldc0 + col] = v;
                    else C0[(size_t)row * ldc0 + col] = f2bf(v);
                } else {
                    if constexpr (std::is_same_v<CT, float>) C1[(size_t)row * ldc1 + col - nsplit] = v;
                    else C1[(size_t)row * ldc1 + col - nsplit] = f2bf(v);
                }
            }
        }
    }
}

// ---------------------------------------------------------------------------
// G4 GEMM with scatter epilogue (BK=32; K=512 short loop).
//   even blockIdx.x: d < 128 -> Kn[row][h*128+d] (coalesced)
//   odd  blockIdx.x: d >= 128 -> VT via LDS transpose, coalesced 64B runs
// ---------------------------------------------------------------------------
__global__ __launch_bounds__(256) void gemm_kv(
    const unsigned short* __restrict__ A, const unsigned short* __restrict__ Bt,
    unsigned short* __restrict__ Kn, unsigned short* __restrict__ VT, int K)
{
    __shared__ __align__(16) unsigned short As[128 * 32];
    __shared__ __align__(16) unsigned short Bs[128 * 32];
    __shared__ __align__(16) unsigned short Ts[64][136];   // transpose buffer

    const int t = threadIdx.x, lane = t & 63, w = t >> 6;
    const int lm = lane & 15, quad = lane >> 4;
    const int wm = w >> 1, wn = w & 1;
    const int m0 = blockIdx.y * 128, n0 = blockIdx.x * 128;
    const int srow = lane >> 2, sseg = lane & 3;

    vfloat4 acc[4][4] = {};

    for (int k0 = 0; k0 < K; k0 += 32) {
        #pragma unroll
        for (int j = 0; j < 2; ++j) {
            int r = w * 32 + j * 16 + srow;
            gload16(A  + (size_t)(m0 + r) * K + k0 + sseg * 8, &As[(w * 2 + j) * 512]);
            gload16(Bt + (size_t)(n0 + r) * K + k0 + sseg * 8, &Bs[(w * 2 + j) * 512]);
        }
        __syncthreads();

        vbf16x8 af[4], bw[4];
        #pragma unroll
        for (int i = 0; i < 4; ++i) {
            af[i] = *(const vbf16x8*)&As[(wm * 64 + i * 16 + lm) * 32 + quad * 8];
            bw[i] = *(const vbf16x8*)&Bs[(wn * 64 + i * 16 + lm) * 32 + quad * 8];
        }
        #pragma unroll
        for (int mi = 0; mi < 4; ++mi)
            #pragma unroll
            for (int ni = 0; ni < 4; ++ni)
                acc[mi][ni] = __builtin_amdgcn_mfma_f32_16x16x32_bf16(af[mi], bw[ni], acc[mi][ni], 0, 0, 0);
        __syncthreads();
    }

    if (!(blockIdx.x & 1)) {
        const int hh = blockIdx.x >> 1;
        #pragma unroll
        for (int mi = 0; mi < 4; ++mi) {
            #pragma unroll
            for (int ni = 0; ni < 4; ++ni) {
                int d = wn * 64 + ni * 16 + lm;
                #pragma unroll
                for (int r = 0; r < 4; ++r) {
                    int row = m0 + wm * 64 + mi * 16 + quad * 4 + r;
                    Kn[(size_t)row * 2048 + hh * 128 + d] = f2bf(acc[mi][ni][r]);
                }
            }
        }
    } else {
        const int hh   = blockIdx.x >> 1;       // head
        const int bb   = m0 >> 11;              // batch
        const int tok0 = m0 & 2047;             // first token of tile
        #pragma unroll
        for (int half = 0; half < 2; ++half) {
            if (wn == half) {
                #pragma unroll
                for (int mi = 0; mi < 4; ++mi) {
                    #pragma unroll
                    for (int ni = 0; ni < 4; ++ni) {
                        int ln = ni * 16 + lm;                    // 0..63
                        int rt = wm * 64 + mi * 16 + quad * 4;    // 0..124
                        #pragma unroll
                        for (int r = 0; r < 4; ++r)
                            Ts[ln][rt + r] = f2bf(acc[mi][ni][r]);
                    }
                }
            }
            __syncthreads();
            {
                int tr = t >> 2, seg = t & 3;    // 64 rows x 4 segments
                int dv = half * 64 + tr;
                unsigned short* dst =
                    VT + ((size_t)(bb * 16 + hh) * 128 + dv) * 2048 + tok0 + seg * 32;
                const unsigned short* srcp = &Ts[tr][seg * 32];
                #pragma unroll
                for (int j = 0; j < 4; ++j)
                    *(vshort8*)(dst + j * 8) = *(const vshort8*)(srcp + j * 8);
            }
            __syncthreads();
        }
    }
}

// ---------------------------------------------------------------------------
// RMSNorm (bf16 activations, fp32 weight)
// ---------------------------------------------------------------------------
__global__ __launch_bounds__(256) void rmsnorm_kernel(
    const unsigned short* __restrict__ in, const float* __restrict__ wgt,
    unsigned short* __restrict__ out, int width, int ld_in, int ld_out)
{
    const int row = blockIdx.x;
    const int t = threadIdx.x;
    const unsigned short* x = in + (size_t)row * ld_in;

    float ss = 0.f;
    for (int i = t; i < width; i += 256) { float v = bf2f(x[i]); ss += v * v; }
    #pragma unroll
    for (int off = 32; off > 0; off >>= 1) ss += __shfl_down(ss, off, 64);

    __shared__ float red[4];
    __shared__ float rr;
    if ((t & 63) == 0) red[t >> 6] = ss;
    __syncthreads();
    if (t == 0) rr = rsqrtf((red[0] + red[1] + red[2] + red[3]) / (float)width + 1e-6f);
    __syncthreads();
    float r = rr;
    unsigned short* o = out + (size_t)row * ld_out;
    for (int i = t; i < width; i += 256) o[i] = f2bf(bf2f(x[i]) * r * wgt[i]);
}

// ---------------------------------------------------------------------------
// RoPE on q_pe, PE dims only (SCALE pre-folded into w_qb at wtrans time).
// ---------------------------------------------------------------------------
__global__ __launch_bounds__(256) void rope_q_kernel(
    unsigned short* __restrict__ q, const float* __restrict__ cosb,
    const float* __restrict__ sinb)
{
    const int row = blockIdx.x;
    const int s = row & 2047;
    const int t = threadIdx.x;
    unsigned short* qr = q + (size_t)row * 3072;
    const int i = t & 31;                 // pair index, same for both c-iters
    const float cs = cosb[s * 64 + i];
    const float sn = sinb[s * 64 + i];

    #pragma unroll
    for (int c = t; c < 512; c += 256) {
        int h = c >> 5;
        unsigned short* p = qr + h * 192 + 128 + i;
        float x = bf2f(p[0]);
        float y = bf2f(p[32]);
        p[0]  = f2bf(x * cs - y * sn);
        p[32] = f2bf(y * cs + x * sn);
    }
}

// ---------------------------------------------------------------------------
// RoPE on k_pe: ckv[:, 512:576] -> kpe[token][64]
// ---------------------------------------------------------------------------
__global__ __launch_bounds__(64) void rope_k_kernel(
    const unsigned short* __restrict__ ckv, const float* __restrict__ cosb,
    const float* __restrict__ sinb, unsigned short* __restrict__ kpe)
{
    const int row = blockIdx.x;
    const int s = row & 2047;
    const int t = threadIdx.x;
    if (t < 32) {
        float cs = cosb[s * 64 + t];
        float sn = sinb[s * 64 + t];
        float x = bf2f(ckv[(size_t)row * 576 + 512 + t]);
        float y = bf2f(ckv[(size_t)row * 576 + 544 + t]);
        kpe[(size_t)row * 64 + t]      = f2bf(x * cs - y * sn);
        kpe[(size_t)row * 64 + 32 + t] = f2bf(y * cs + x * sn);
    }
}

// ---------------------------------------------------------------------------
// Causal flash attention — round-7 proven body (127.4 us, 104 VGPR): paired
// q-tiles, V staged in LDS, flat 512-block grid with XCD co-location
// (bid&31 = (h,b) group -> FETCH 263->36 MB).
// Round-10 single change (resubmitted after infra fail): the mid-iteration
// barrier between the P->Ps[w] write and the PV read is REMOVED — Ps is
// wave-private (written and read with the wave's own w), V/K come from
// Vs/global, and Ks is not rewritten until after the post-PV barrier.
// Within-wave LDS write->read ordering is guaranteed by lgkmcnt. Deletes 33
// full vmcnt/lgkmcnt drains per block.
// History: r1/r2/r9 = any added live state or per-MFMA global loads spill
// (VGPR sinks to 84, 2x slower). r4 = biggest-first de-pair stragglers.
// r8/r9 = V-direct-from-global serializes PV on L2 latency. Do not repeat.
// ---------------------------------------------------------------------------
__global__ __launch_bounds__(256) void flash_kernel(
    const unsigned short* __restrict__ Q, const unsigned short* __restrict__ Kn,
    const unsigned short* __restrict__ KPE, const unsigned short* __restrict__ VT,
    unsigned short* __restrict__ O)
{
    __shared__ __align__(16) unsigned short Ks[64][200];
    __shared__ __align__(16) unsigned short Vs[128][72];
    __shared__ __align__(16) unsigned short Ps[4][16][72];

    const int t    = threadIdx.x;
    const int lane = t & 63;
    const int w    = t >> 6;
    const int lm   = lane & 15, quad = lane >> 4;
    const int bid = blockIdx.x;
    const int g = bid & 31;          // (h,b) group: same-g -> same XCD (r7)
    const int m = bid >> 5;          // q-pair index 0..15
    const int h = g & 15, b = g >> 4;
    const int tb = b * 2048;
    const unsigned short* VTbh = VT + (size_t)(b * 16 + h) * 128 * 2048;

    for (int pi = 0; pi < 2; ++pi) {
        const int qt = pi ? (31 - m) : m;

        const int qtok = tb + qt * 64 + w * 16 + lm;
        vbf16x8 aq[6];
        #pragma unroll
        for (int ch = 0; ch < 6; ++ch)
            aq[ch] = *(const vbf16x8*)(Q + (size_t)qtok * 3072 + h * 192 + ch * 32 + quad * 8);

        vfloat4 acc_o[8];
        #pragma unroll
        for (int i = 0; i < 8; ++i) acc_o[i] = (vfloat4){0, 0, 0, 0};
        float mrow[4], lrow[4];
        #pragma unroll
        for (int r = 0; r < 4; ++r) { mrow[r] = -3.0e38f; lrow[r] = 0.f; }

        for (int kt = 0; kt <= qt; ++kt) {
            const int kb = kt * 64;
            // stage K_nope (contiguous 128-short rows of Kn)
            #pragma unroll
            for (int it = 0; it < 4; ++it) {
                int idx = t + it * 256;
                int row = idx >> 4, sg = idx & 15;
                *(vshort8*)&Ks[row][sg * 8] =
                    *(const vshort8*)(Kn + (size_t)(tb + kb + row) * 2048 + h * 128 + sg * 8);
            }
            // stage K_pe
            #pragma unroll
            for (int it = 0; it < 2; ++it) {
                int idx = t + it * 256;
                int row = idx >> 3, sg = idx & 7;
                *(vshort8*)&Ks[row][128 + sg * 8] =
                    *(const vshort8*)(KPE + (size_t)(tb + kb + row) * 64 + sg * 8);
            }
            // stage V (already transposed in global: rows d, cols tokens)
            #pragma unroll
            for (int it = 0; it < 4; ++it) {
                int idx = t + it * 256;
                int d = idx >> 3, sg = idx & 7;
                *(vshort8*)&Vs[d][sg * 8] =
                    *(const vshort8*)(VTbh + (size_t)d * 2048 + kb + sg * 8);
            }
            __syncthreads();   // (1) staging complete before any reads

            // S = Q K^T (wave strip: 16 q x 64 k)
            vfloat4 accs[4];
            #pragma unroll
            for (int ni = 0; ni < 4; ++ni) accs[ni] = (vfloat4){0, 0, 0, 0};
            #pragma unroll
            for (int ni = 0; ni < 4; ++ni) {
                #pragma unroll
                for (int ch = 0; ch < 6; ++ch) {
                    vbf16x8 bk = *(const vbf16x8*)&Ks[ni * 16 + lm][ch * 32 + quad * 8];
                    accs[ni] = __builtin_amdgcn_mfma_f32_16x16x32_bf16(aq[ch], bk, accs[ni], 0, 0, 0);
                }
            }

            // causal mask
            const int qrow = qt * 64 + w * 16 + quad * 4;
            #pragma unroll
            for (int ni = 0; ni < 4; ++ni) {
                int ki = kb + ni * 16 + lm;
                #pragma unroll
                for (int r = 0; r < 4; ++r)
                    if (ki > qrow + r) accs[ni][r] = -3.0e38f;
            }

            // online softmax
            #pragma unroll
            for (int r = 0; r < 4; ++r) {
                float mx = fmaxf(fmaxf(accs[0][r], accs[1][r]), fmaxf(accs[2][r], accs[3][r]));
                #pragma unroll
                for (int off = 1; off < 16; off <<= 1) mx = fmaxf(mx, __shfl_xor(mx, off, 64));
                float mnew  = fmaxf(mrow[r], mx);
                float alpha = __expf(mrow[r] - mnew);
                float sum = 0.f;
                #pragma unroll
                for (int ni = 0; ni < 4; ++ni) {
                    float pv = __expf(accs[ni][r] - mnew);
                    accs[ni][r] = pv;
                    sum += pv;
                }
                #pragma unroll
                for (int off = 1; off < 16; off <<= 1) sum += __shfl_xor(sum, off, 64);
                lrow[r] = lrow[r] * alpha + sum;
                mrow[r] = mnew;
                #pragma unroll
                for (int vt = 0; vt < 8; ++vt) acc_o[vt][r] *= alpha;
            }

            // P: C-layout -> LDS -> A-layout. Ps[w] is wave-private: no
            // barrier needed between this write and the PV read below
            // (within-wave DS ordering via lgkmcnt). [round-10 change]
            #pragma unroll
            for (int ni = 0; ni < 4; ++ni)
                #pragma unroll
                for (int r = 0; r < 4; ++r)
                    Ps[w][quad * 4 + r][ni * 16 + lm] = f2bf(accs[ni][r]);

            // O += P V
            #pragma unroll
            for (int kc = 0; kc < 2; ++kc) {
                vbf16x8 ap = *(const vbf16x8*)&Ps[w][lm][kc * 32 + quad * 8];
                #pragma unroll
                for (int vt = 0; vt < 8; ++vt) {
                    vbf16x8 bv = *(const vbf16x8*)&Vs[vt * 16 + lm][kc * 32 + quad * 8];
                    acc_o[vt] = __builtin_amdgcn_mfma_f32_16x16x32_bf16(ap, bv, acc_o[vt], 0, 0, 0);
                }
            }
            __syncthreads();   // (3) PV reads of Ks/Vs done before next staging
        }

        #pragma unroll
        for (int r = 0; r < 4; ++r) {
            float inv = 1.f / lrow[r];
            int tok = tb + qt * 64 + w * 16 + quad * 4 + r;
            #pragma unroll
            for (int vt = 0; vt < 8; ++vt)
                O[(size_t)tok * 2048 + h * 128 + vt * 16 + lm] = f2bf(acc_o[vt][r] * inv);
        }
    }
}

// ---------------------------------------------------------------------------
extern "C" void kernel_launch(void* const* d_in, const int* in_sizes, int n_in,
                              void* d_out, int out_size, void* d_ws, size_t ws_size,
                              hipStream_t stream) {
    const float* hidden = (const float*)d_in[0];
    // d_in[1] = attention_mask (pure causal; applied analytically)
    const float* cosb   = (const float*)d_in[2];
    const float* sinb   = (const float*)d_in[3];
    const float* w_qa   = (const float*)d_in[4];
    const float* qa_ln  = (const float*)d_in[5];
    const float* w_qb   = (const float*)d_in[6];
    const float* w_kva  = (const float*)d_in[7];
    const float* kva_ln = (const float*)d_in[8];
    const float* w_kvb  = (const float*)d_in[9];
    const float* w_o    = (const float*)d_in[10];
    float* out = (float*)d_out;
    const float SCALE = 0.07216878364870323f;  // 192^-0.5, folded into w_qb

    // Workspace overlays (ushort units). Peak 47,185,920 u = 94.4 MB
    unsigned short* ws   = (unsigned short*)d_ws;
    unsigned short* hb   = ws;                  // 4096x2048 [hconv..G1G2]
    unsigned short* Kn   = ws;                  // 4096x2048 [G4..flash]
    unsigned short* wt12 = ws + 8388608;        // 2176x2048 [prep..G1G2]
    unsigned short* VT   = ws + 8388608;        // 32x128x2048 [G4..flash]
    unsigned short* ot   = ws + 8388608;        // 2048x2048 [post-flash..G5]
    unsigned short* qbuf = ws + 16777216;       // 4096x3072
    unsigned short* q_a  = ws + 29360128;       // 4096x1536 [G1G2..G3]
    unsigned short* ckv  = ws + 35651584;       // 4096x576  [G1G2..rope_k]
    unsigned short* aout = ws + 29360128;       // 4096x2048 [flash..G5]
    unsigned short* qbt  = ws + 38010880;       // 3072x1536
    unsigned short* kvbt = ws + 42729472;       // 4096x512
    unsigned short* kvn  = ws + 44826624;       // 4096x512
    unsigned short* kpe  = ws + 46923776;       // 4096x64   -> end 47185920

    dim3 blk(256);

    // Prepass: hidden -> bf16; weights -> bf16 transposed (N-major rows, K cols)
    hconv_kernel<<<4096, blk, 0, stream>>>(hidden, hb, 1048576);
    wtrans_kernel<<<dim3(24, 32), blk, 0, stream>>>(w_qa,  wt12, 1536, 2048, 0,    1.0f);
    wtrans_kernel<<<dim3( 9, 32), blk, 0, stream>>>(w_kva, wt12,  576, 2048, 1536, 1.0f);
    wtrans_kernel<<<dim3(48, 24), blk, 0, stream>>>(w_qb,  qbt,  3072, 1536, 0,    SCALE);
    wtrans_kernel<<<dim3(64,  8), blk, 0, stream>>>(w_kvb, kvbt, 4096,  512, 0,    1.0f);

    // G1+G2 fused: [q_a | ckv] = hidden @ [w_qa | w_kva]  (N=2112, split 1536)
    gemm_tt<unsigned short><<<dim3(17, 32), blk, 0, stream>>>(
        hb, wt12, q_a, ckv, 2048, 2112, 1536, 1536, 576);

    rmsnorm_kernel<<<4096, blk, 0, stream>>>(q_a, qa_ln, q_a, 1536, 1536, 1536);
    rmsnorm_kernel<<<4096, blk, 0, stream>>>(ckv, kva_ln, kvn, 512, 576, 512);
    rope_k_kernel<<<4096, dim3(64), 0, stream>>>(ckv, cosb, sinb, kpe);

    // G3: qbuf = q_a_norm @ w_qb (pre-scaled); then rope (PE dims only)
    gemm_tt<unsigned short><<<dim3(24, 32), blk, 0, stream>>>(
        q_a, qbt, qbuf, qbuf, 1536, 3072, 3072, 3072, 3072);
    rope_q_kernel<<<4096, blk, 0, stream>>>(qbuf, cosb, sinb);

    // G4: [Kn | VT] = kv_norm @ w_kvb  (split epilogue, coalesced VT)
    gemm_kv<<<dim3(32, 32), blk, 0, stream>>>(kvn, kvbt, Kn, VT, 512);

    // attention: flat grid, XCD-co-located (h,b) groups, paired q-tiles
    flash_kernel<<<dim3(512), blk, 0, stream>>>(qbuf, Kn, kpe, VT, aout);

    // w_o transpose (deferred: reuses VT region after flash)
    wtrans_kernel<<<dim3(32, 32), blk, 0, stream>>>(w_o, ot, 2048, 2048, 0, 1.0f);

    // G5: out = attn_out @ w_o (fp32 output)
    gemm_tt<float><<<dim3(16, 32), blk, 0, stream>>>(
        aout, ot, out, out, 2048, 2048, 2048, 2048, 2048);
}

// Round 12
// 508.945 us; speedup vs baseline: 1.1588x; 1.0902x over previous
//
#include <hip/hip_runtime.h>
#include <type_traits>

typedef __attribute__((ext_vector_type(8))) short  vshort8;
typedef __attribute__((ext_vector_type(8))) __bf16 vbf16x8;
typedef __attribute__((ext_vector_type(4))) float  vfloat4;

__device__ __forceinline__ float bf2f(unsigned short h) {
    return __uint_as_float(((unsigned int)h) << 16);
}
__device__ __forceinline__ unsigned short f2bf(float f) {
    unsigned int u = __float_as_uint(f);
    unsigned int r = (u + 0x7FFFu + ((u >> 16) & 1u)) >> 16;
    return (unsigned short)r;
}
__device__ __forceinline__ vshort8 cvt8s(const float* p, float s) {
    float4 a = *(const float4*)p;
    float4 b = *(const float4*)(p + 4);
    vshort8 r;
    r[0] = (short)f2bf(a.x * s); r[1] = (short)f2bf(a.y * s);
    r[2] = (short)f2bf(a.z * s); r[3] = (short)f2bf(a.w * s);
    r[4] = (short)f2bf(b.x * s); r[5] = (short)f2bf(b.y * s);
    r[6] = (short)f2bf(b.z * s); r[7] = (short)f2bf(b.w * s);
    return r;
}
__device__ __forceinline__ vshort8 cvt8(const float* p) { return cvt8s(p, 1.0f); }
// async global->LDS, 16B per lane; LDS base must be wave-uniform.
__device__ __forceinline__ void gload16(const void* g, void* lds) {
    __builtin_amdgcn_global_load_lds(
        (const __attribute__((address_space(1))) unsigned int*)g,
        (__attribute__((address_space(3))) unsigned int*)lds, 16, 0, 0);
}

// ---------------------------------------------------------------------------
// fp32 -> bf16 bulk convert (hidden states)
// ---------------------------------------------------------------------------
__global__ __launch_bounds__(256) void hconv_kernel(
    const float* __restrict__ in, unsigned short* __restrict__ out, int n8)
{
    int i = blockIdx.x * 256 + threadIdx.x;
    if (i < n8) *(vshort8*)(out + (size_t)i * 8) = cvt8(in + (size_t)i * 8);
}

// ---------------------------------------------------------------------------
// Weight transpose+convert: W[K][N] fp32 -> Wt[rowoff+n][K] bf16, times scale.
// ---------------------------------------------------------------------------
__global__ __launch_bounds__(256) void wtrans_kernel(
    const float* __restrict__ W, unsigned short* __restrict__ Wt,
    int ldw, int ldt, int rowoff, float scale)
{
    __shared__ __align__(16) unsigned short Ls[64][72];
    const int t = threadIdx.x;
    const int n0 = blockIdx.x * 64, k0 = blockIdx.y * 64;
    const int rr = t >> 2, cc = t & 3;   // rr: 0..63, cc: 0..3

    const float* src = W + (size_t)(k0 + rr) * ldw + n0 + cc * 16;
    *(vshort8*)&Ls[rr][cc * 16]     = cvt8s(src, scale);
    *(vshort8*)&Ls[rr][cc * 16 + 8] = cvt8s(src + 8, scale);
    __syncthreads();

    unsigned short* dst = Wt + (size_t)(rowoff + n0 + rr) * ldt + k0 + cc * 16;
    vshort8 v0, v1;
    #pragma unroll
    for (int j = 0; j < 8; ++j) {
        v0[j] = (short)Ls[cc * 16 + j][rr];
        v1[j] = (short)Ls[cc * 16 + 8 + j][rr];
    }
    *(vshort8*)dst = v0;
    *(vshort8*)(dst + 8) = v1;
}

// ---------------------------------------------------------------------------
// m97-style GEMM, BK=64 (round-6 win). LDS LINEAR [128][64] for
// global_load_lds; bank wrap broken by row-parity half-swap on BOTH sides
// (rule #21): global SOURCE column XORs its 32-col half with (row&1);
// ds_read applies the same XOR (kk ^ (lm&1)). 32KB LDS. K % 64 == 0.
// Round-12: XCD-aware block remap (T1, mapping-only). Default linear
// dispatch scatters same-y blocks (sharing one A-row-panel) across all 8
// XCD L2s. Remap: c=bid&7, j=bid>>3 -> bx=j%nbx, by=c+8*(j/nbx); each XCD
// owns 4 y-panels (<=2MB, fits 4MB L2) while x sweeps B. Bijective when
// nby%8==0 (all gemm_tt grids here have nby=32). Equal-work permutation:
// wrong XCD-mapping assumption degrades to neutral, not a regression.
// ---------------------------------------------------------------------------
template<typename CT>
__global__ __launch_bounds__(256) void gemm_tt(
    const unsigned short* __restrict__ A, const unsigned short* __restrict__ Bt,
    CT* __restrict__ C0, CT* __restrict__ C1,
    int K, int N, int nsplit, int ldc0, int ldc1)
{
    __shared__ __align__(16) unsigned short As[128 * 64];
    __shared__ __align__(16) unsigned short Bs[128 * 64];

    const int t = threadIdx.x, lane = t & 63, w = t >> 6;
    const int lm = lane & 15, quad = lane >> 4;
    const int wm = w >> 1, wn = w & 1;
    const int nbx = gridDim.x;
    const int bid = blockIdx.y * nbx + blockIdx.x;
    const int c = bid & 7, j = bid >> 3;
    const int m0 = (c + 8 * (j / nbx)) * 128;   // y-panel pinned to XCD c
    const int n0 = (j % nbx) * 128;
    const int srow = lane >> 3, sseg = lane & 7;
    const int scol = (((sseg >> 2) ^ (srow & 1)) << 5) + (sseg & 3) * 8;

    vfloat4 acc[4][4] = {};

    for (int k0 = 0; k0 < K; k0 += 64) {
        #pragma unroll
        for (int jj = 0; jj < 4; ++jj) {
            int r = w * 32 + jj * 8 + srow;
            gload16(A  + (size_t)(m0 + r) * K + k0 + scol, &As[(w * 32 + jj * 8) * 64]);
            gload16(Bt + (size_t)(n0 + r) * K + k0 + scol, &Bs[(w * 32 + jj * 8) * 64]);
        }
        __syncthreads();

        #pragma unroll
        for (int kk = 0; kk < 2; ++kk) {
            const int xo = ((kk ^ (lm & 1)) << 5) + quad * 8;  // de-swizzle
            vbf16x8 af[4], bw[4];
            #pragma unroll
            for (int i = 0; i < 4; ++i) {
                af[i] = *(const vbf16x8*)&As[(wm * 64 + i * 16 + lm) * 64 + xo];
                bw[i] = *(const vbf16x8*)&Bs[(wn * 64 + i * 16 + lm) * 64 + xo];
            }
            #pragma unroll
            for (int mi = 0; mi < 4; ++mi)
                #pragma unroll
                for (int ni = 0; ni < 4; ++ni)
                    acc[mi][ni] = __builtin_amdgcn_mfma_f32_16x16x32_bf16(af[mi], bw[ni], acc[mi][ni], 0, 0, 0);
        }
        __syncthreads();
    }

    #pragma unroll
    for (int mi = 0; mi < 4; ++mi) {
        #pragma unroll
        for (int ni = 0; ni < 4; ++ni) {
            int col = n0 + wn * 64 + ni * 16 + lm;
            if (col >= N) continue;
            #pragma unroll
            for (int r = 0; r < 4; ++r) {
                int row = m0 + wm * 64 + mi * 16 + quad * 4 + r;
                float v = acc[mi][ni][r];
                if (col < nsplit) {
                    if constexpr (std::is_same_v<CT, float>) C0[(size_t)row * ldc0 + col] = v;
                    else C0[(size_t)row * ldc0 + col] = f2bf(v);
                } else {
                    if constexpr (std::is_same_v<CT, float>) C1[(size_t)row * ldc1 + col - nsplit] = v;
                    else C1[(size_t)row * ldc1 + col - nsplit] = f2bf(v);
                }
            }
        }
    }
}

// ---------------------------------------------------------------------------
// G4 GEMM with scatter epilogue (BK=32; K=512 short loop).
//   even blockIdx.x: d < 128 -> Kn[row][h*128+d] (coalesced)
//   odd  blockIdx.x: d >= 128 -> VT via LDS transpose, coalesced 64B runs
// ---------------------------------------------------------------------------
__global__ __launch_bounds__(256) void gemm_kv(
    const unsigned short* __restrict__ A, const unsigned short* __restrict__ Bt,
    unsigned short* __restrict__ Kn, unsigned short* __restrict__ VT, int K)
{
    __shared__ __align__(16) unsigned short As[128 * 32];
    __shared__ __align__(16) unsigned short Bs[128 * 32];
    __shared__ __align__(16) unsigned short Ts[64][136];   // transpose buffer

    const int t = threadIdx.x, lane = t & 63, w = t >> 6;
    const int lm = lane & 15, quad = lane >> 4;
    const int wm = w >> 1, wn = w & 1;
    const int m0 = blockIdx.y * 128, n0 = blockIdx.x * 128;
    const int srow = lane >> 2, sseg = lane & 3;

    vfloat4 acc[4][4] = {};

    for (int k0 = 0; k0 < K; k0 += 32) {
        #pragma unroll
        for (int j = 0; j < 2; ++j) {
            int r = w * 32 + j * 16 + srow;
            gload16(A  + (size_t)(m0 + r) * K + k0 + sseg * 8, &As[(w * 2 + j) * 512]);
            gload16(Bt + (size_t)(n0 + r) * K + k0 + sseg * 8, &Bs[(w * 2 + j) * 512]);
        }
        __syncthreads();

        vbf16x8 af[4], bw[4];
        #pragma unroll
        for (int i = 0; i < 4; ++i) {
            af[i] = *(const vbf16x8*)&As[(wm * 64 + i * 16 + lm) * 32 + quad * 8];
            bw[i] = *(const vbf16x8*)&Bs[(wn * 64 + i * 16 + lm) * 32 + quad * 8];
        }
        #pragma unroll
        for (int mi = 0; mi < 4; ++mi)
            #pragma unroll
            for (int ni = 0; ni < 4; ++ni)
                acc[mi][ni] = __builtin_amdgcn_mfma_f32_16x16x32_bf16(af[mi], bw[ni], acc[mi][ni], 0, 0, 0);
        __syncthreads();
    }

    if (!(blockIdx.x & 1)) {
        const int hh = blockIdx.x >> 1;
        #pragma unroll
        for (int mi = 0; mi < 4; ++mi) {
            #pragma unroll
            for (int ni = 0; ni < 4; ++ni) {
                int d = wn * 64 + ni * 16 + lm;
                #pragma unroll
                for (int r = 0; r < 4; ++r) {
                    int row = m0 + wm * 64 + mi * 16 + quad * 4 + r;
                    Kn[(size_t)row * 2048 + hh * 128 + d] = f2bf(acc[mi][ni][r]);
                }
            }
        }
    } else {
        const int hh   = blockIdx.x >> 1;       // head
        const int bb   = m0 >> 11;              // batch
        const int tok0 = m0 & 2047;             // first token of tile
        #pragma unroll
        for (int half = 0; half < 2; ++half) {
            if (wn == half) {
                #pragma unroll
                for (int mi = 0; mi < 4; ++mi) {
                    #pragma unroll
                    for (int ni = 0; ni < 4; ++ni) {
                        int ln = ni * 16 + lm;                    // 0..63
                        int rt = wm * 64 + mi * 16 + quad * 4;    // 0..124
                        #pragma unroll
                        for (int r = 0; r < 4; ++r)
                            Ts[ln][rt + r] = f2bf(acc[mi][ni][r]);
                    }
                }
            }
            __syncthreads();
            {
                int tr = t >> 2, seg = t & 3;    // 64 rows x 4 segments
                int dv = half * 64 + tr;
                unsigned short* dst =
                    VT + ((size_t)(bb * 16 + hh) * 128 + dv) * 2048 + tok0 + seg * 32;
                const unsigned short* srcp = &Ts[tr][seg * 32];
                #pragma unroll
                for (int j = 0; j < 4; ++j)
                    *(vshort8*)(dst + j * 8) = *(const vshort8*)(srcp + j * 8);
            }
            __syncthreads();
        }
    }
}

// ---------------------------------------------------------------------------
// RMSNorm (bf16 activations, fp32 weight)
// ---------------------------------------------------------------------------
__global__ __launch_bounds__(256) void rmsnorm_kernel(
    const unsigned short* __restrict__ in, const float* __restrict__ wgt,
    unsigned short* __restrict__ out, int width, int ld_in, int ld_out)
{
    const int row = blockIdx.x;
    const int t = threadIdx.x;
    const unsigned short* x = in + (size_t)row * ld_in;

    float ss = 0.f;
    for (int i = t; i < width; i += 256) { float v = bf2f(x[i]); ss += v * v; }
    #pragma unroll
    for (int off = 32; off > 0; off >>= 1) ss += __shfl_down(ss, off, 64);

    __shared__ float red[4];
    __shared__ float rr;
    if ((t & 63) == 0) red[t >> 6] = ss;
    __syncthreads();
    if (t == 0) rr = rsqrtf((red[0] + red[1] + red[2] + red[3]) / (float)width + 1e-6f);
    __syncthreads();
    float r = rr;
    unsigned short* o = out + (size_t)row * ld_out;
    for (int i = t; i < width; i += 256) o[i] = f2bf(bf2f(x[i]) * r * wgt[i]);
}

// ---------------------------------------------------------------------------
// RoPE on q_pe, PE dims only (SCALE pre-folded into w_qb at wtrans time).
// ---------------------------------------------------------------------------
__global__ __launch_bounds__(256) void rope_q_kernel(
    unsigned short* __restrict__ q, const float* __restrict__ cosb,
    const float* __restrict__ sinb)
{
    const int row = blockIdx.x;
    const int s = row & 2047;
    const int t = threadIdx.x;
    unsigned short* qr = q + (size_t)row * 3072;
    const int i = t & 31;                 // pair index, same for both c-iters
    const float cs = cosb[s * 64 + i];
    const float sn = sinb[s * 64 + i];

    #pragma unroll
    for (int c = t; c < 512; c += 256) {
        int h = c >> 5;
        unsigned short* p = qr + h * 192 + 128 + i;
        float x = bf2f(p[0]);
        float y = bf2f(p[32]);
        p[0]  = f2bf(x * cs - y * sn);
        p[32] = f2bf(y * cs + x * sn);
    }
}

// ---------------------------------------------------------------------------
// RoPE on k_pe: ckv[:, 512:576] -> kpe[token][64]
// ---------------------------------------------------------------------------
__global__ __launch_bounds__(64) void rope_k_kernel(
    const unsigned short* __restrict__ ckv, const float* __restrict__ cosb,
    const float* __restrict__ sinb, unsigned short* __restrict__ kpe)
{
    const int row = blockIdx.x;
    const int s = row & 2047;
    const int t = threadIdx.x;
    if (t < 32) {
        float cs = cosb[s * 64 + t];
        float sn = sinb[s * 64 + t];
        float x = bf2f(ckv[(size_t)row * 576 + 512 + t]);
        float y = bf2f(ckv[(size_t)row * 576 + 544 + t]);
        kpe[(size_t)row * 64 + t]      = f2bf(x * cs - y * sn);
        kpe[(size_t)row * 64 + 32 + t] = f2bf(y * cs + x * sn);
    }
}

// ---------------------------------------------------------------------------
// Causal flash attention — EXACT round-7 kernel (127.4 us, 104 VGPR, proven):
// paired q-tiles, V staged in LDS, flat 512-block grid, XCD co-location
// (bid&31 = (h,b) group -> FETCH 263->36 MB), THREE barriers per k-iter.
// Hard-won constraints (do not violate):
//  * r1/r2/r11: ANY change that adds live state or merges scheduling regions
//    (incl. removing the mid barrier) pushes VGPR past the 128 cliff ->
//    occupancy halves. The barriers double as register-pressure fences.
//  * r4: biggest-first de-paired grid -> straggler tail. Balanced pairs win.
//  * r8/r9: V direct-from-global serializes PV on L2 latency (VGPR sinks
//    to 84, loads won't stay in flight).
// ---------------------------------------------------------------------------
__global__ __launch_bounds__(256) void flash_kernel(
    const unsigned short* __restrict__ Q, const unsigned short* __restrict__ Kn,
    const unsigned short* __restrict__ KPE, const unsigned short* __restrict__ VT,
    unsigned short* __restrict__ O)
{
    __shared__ __align__(16) unsigned short Ks[64][200];
    __shared__ __align__(16) unsigned short Vs[128][72];
    __shared__ __align__(16) unsigned short Ps[4][16][72];

    const int t    = threadIdx.x;
    const int lane = t & 63;
    const int w    = t >> 6;
    const int lm   = lane & 15, quad = lane >> 4;
    const int bid = blockIdx.x;
    const int g = bid & 31;          // (h,b) group: same-g -> same XCD (r7)
    const int m = bid >> 5;          // q-pair index 0..15
    const int h = g & 15, b = g >> 4;
    const int tb = b * 2048;
    const unsigned short* VTbh = VT + (size_t)(b * 16 + h) * 128 * 2048;

    for (int pi = 0; pi < 2; ++pi) {
        const int qt = pi ? (31 - m) : m;

        const int qtok = tb + qt * 64 + w * 16 + lm;
        vbf16x8 aq[6];
        #pragma unroll
        for (int ch = 0; ch < 6; ++ch)
            aq[ch] = *(const vbf16x8*)(Q + (size_t)qtok * 3072 + h * 192 + ch * 32 + quad * 8);

        vfloat4 acc_o[8];
        #pragma unroll
        for (int i = 0; i < 8; ++i) acc_o[i] = (vfloat4){0, 0, 0, 0};
        float mrow[4], lrow[4];
        #pragma unroll
        for (int r = 0; r < 4; ++r) { mrow[r] = -3.0e38f; lrow[r] = 0.f; }

        for (int kt = 0; kt <= qt; ++kt) {
            const int kb = kt * 64;
            // stage K_nope (contiguous 128-short rows of Kn)
            #pragma unroll
            for (int it = 0; it < 4; ++it) {
                int idx = t + it * 256;
                int row = idx >> 4, sg = idx & 15;
                *(vshort8*)&Ks[row][sg * 8] =
                    *(const vshort8*)(Kn + (size_t)(tb + kb + row) * 2048 + h * 128 + sg * 8);
            }
            // stage K_pe
            #pragma unroll
            for (int it = 0; it < 2; ++it) {
                int idx = t + it * 256;
                int row = idx >> 3, sg = idx & 7;
                *(vshort8*)&Ks[row][128 + sg * 8] =
                    *(const vshort8*)(KPE + (size_t)(tb + kb + row) * 64 + sg * 8);
            }
            // stage V (already transposed in global: rows d, cols tokens)
            #pragma unroll
            for (int it = 0; it < 4; ++it) {
                int idx = t + it * 256;
                int d = idx >> 3, sg = idx & 7;
                *(vshort8*)&Vs[d][sg * 8] =
                    *(const vshort8*)(VTbh + (size_t)d * 2048 + kb + sg * 8);
            }
            __syncthreads();

            // S = Q K^T (wave strip: 16 q x 64 k)
            vfloat4 accs[4];
            #pragma unroll
            for (int ni = 0; ni < 4; ++ni) accs[ni] = (vfloat4){0, 0, 0, 0};
            #pragma unroll
            for (int ni = 0; ni < 4; ++ni) {
                #pragma unroll
                for (int ch = 0; ch < 6; ++ch) {
                    vbf16x8 bk = *(const vbf16x8*)&Ks[ni * 16 + lm][ch * 32 + quad * 8];
                    accs[ni] = __builtin_amdgcn_mfma_f32_16x16x32_bf16(aq[ch], bk, accs[ni], 0, 0, 0);
                }
            }

            // causal mask
            const int qrow = qt * 64 + w * 16 + quad * 4;
            #pragma unroll
            for (int ni = 0; ni < 4; ++ni) {
                int ki = kb + ni * 16 + lm;
                #pragma unroll
                for (int r = 0; r < 4; ++r)
                    if (ki > qrow + r) accs[ni][r] = -3.0e38f;
            }

            // online softmax
            #pragma unroll
            for (int r = 0; r < 4; ++r) {
                float mx = fmaxf(fmaxf(accs[0][r], accs[1][r]), fmaxf(accs[2][r], accs[3][r]));
                #pragma unroll
                for (int off = 1; off < 16; off <<= 1) mx = fmaxf(mx, __shfl_xor(mx, off, 64));
                float mnew  = fmaxf(mrow[r], mx);
                float alpha = __expf(mrow[r] - mnew);
                float sum = 0.f;
                #pragma unroll
                for (int ni = 0; ni < 4; ++ni) {
                    float pv = __expf(accs[ni][r] - mnew);
                    accs[ni][r] = pv;
                    sum += pv;
                }
                #pragma unroll
                for (int off = 1; off < 16; off <<= 1) sum += __shfl_xor(sum, off, 64);
                lrow[r] = lrow[r] * alpha + sum;
                mrow[r] = mnew;
                #pragma unroll
                for (int vt = 0; vt < 8; ++vt) acc_o[vt][r] *= alpha;
            }

            // P: C-layout -> LDS -> A-layout
            #pragma unroll
            for (int ni = 0; ni < 4; ++ni)
                #pragma unroll
                for (int r = 0; r < 4; ++r)
                    Ps[w][quad * 4 + r][ni * 16 + lm] = f2bf(accs[ni][r]);
            __syncthreads();

            // O += P V
            #pragma unroll
            for (int kc = 0; kc < 2; ++kc) {
                vbf16x8 ap = *(const vbf16x8*)&Ps[w][lm][kc * 32 + quad * 8];
                #pragma unroll
                for (int vt = 0; vt < 8; ++vt) {
                    vbf16x8 bv = *(const vbf16x8*)&Vs[vt * 16 + lm][kc * 32 + quad * 8];
                    acc_o[vt] = __builtin_amdgcn_mfma_f32_16x16x32_bf16(ap, bv, acc_o[vt], 0, 0, 0);
                }
            }
            __syncthreads();
        }

        #pragma unroll
        for (int r = 0; r < 4; ++r) {
            float inv = 1.f / lrow[r];
            int tok = tb + qt * 64 + w * 16 + quad * 4 + r;
            #pragma unroll
            for (int vt = 0; vt < 8; ++vt)
                O[(size_t)tok * 2048 + h * 128 + vt * 16 + lm] = f2bf(acc_o[vt][r] * inv);
        }
    }
}

// ---------------------------------------------------------------------------
extern "C" void kernel_launch(void* const* d_in, const int* in_sizes, int n_in,
                              void* d_out, int out_size, void* d_ws, size_t ws_size,
                              hipStream_t stream) {
    const float* hidden = (const float*)d_in[0];
    // d_in[1] = attention_mask (pure causal; applied analytically)
    const float* cosb   = (const float*)d_in[2];
    const float* sinb   = (const float*)d_in[3];
    const float* w_qa   = (const float*)d_in[4];
    const float* qa_ln  = (const float*)d_in[5];
    const float* w_qb   = (const float*)d_in[6];
    const float* w_kva  = (const float*)d_in[7];
    const float* kva_ln = (const float*)d_in[8];
    const float* w_kvb  = (const float*)d_in[9];
    const float* w_o    = (const float*)d_in[10];
    float* out = (float*)d_out;
    const float SCALE = 0.07216878364870323f;  // 192^-0.5, folded into w_qb

    // Workspace overlays (ushort units). Peak 47,185,920 u = 94.4 MB
    unsigned short* ws   = (unsigned short*)d_ws;
    unsigned short* hb   = ws;                  // 4096x2048 [hconv..G1G2]
    unsigned short* Kn   = ws;                  // 4096x2048 [G4..flash]
    unsigned short* wt12 = ws + 8388608;        // 2176x2048 [prep..G1G2]
    unsigned short* VT   = ws + 8388608;        // 32x128x2048 [G4..flash]
    unsigned short* ot   = ws + 8388608;        // 2048x2048 [post-flash..G5]
    unsigned short* qbuf = ws + 16777216;       // 4096x3072
    unsigned short* q_a  = ws + 29360128;       // 4096x1536 [G1G2..G3]
    unsigned short* ckv  = ws + 35651584;       // 4096x576  [G1G2..rope_k]
    unsigned short* aout = ws + 29360128;       // 4096x2048 [flash..G5]
    unsigned short* qbt  = ws + 38010880;       // 3072x1536
    unsigned short* kvbt = ws + 42729472;       // 4096x512
    unsigned short* kvn  = ws + 44826624;       // 4096x512
    unsigned short* kpe  = ws + 46923776;       // 4096x64   -> end 47185920

    dim3 blk(256);

    // Prepass: hidden -> bf16; weights -> bf16 transposed (N-major rows, K cols)
    hconv_kernel<<<4096, blk, 0, stream>>>(hidden, hb, 1048576);
    wtrans_kernel<<<dim3(24, 32), blk, 0, stream>>>(w_qa,  wt12, 1536, 2048, 0,    1.0f);
    wtrans_kernel<<<dim3( 9, 32), blk, 0, stream>>>(w_kva, wt12,  576, 2048, 1536, 1.0f);
    wtrans_kernel<<<dim3(48, 24), blk, 0, stream>>>(w_qb,  qbt,  3072, 1536, 0,    SCALE);
    wtrans_kernel<<<dim3(64,  8), blk, 0, stream>>>(w_kvb, kvbt, 4096,  512, 0,    1.0f);

    // G1+G2 fused: [q_a | ckv] = hidden @ [w_qa | w_kva]  (N=2112, split 1536)
    gemm_tt<unsigned short><<<dim3(17, 32), blk, 0, stream>>>(
        hb, wt12, q_a, ckv, 2048, 2112, 1536, 1536, 576);

    rmsnorm_kernel<<<4096, blk, 0, stream>>>(q_a, qa_ln, q_a, 1536, 1536, 1536);
    rmsnorm_kernel<<<4096, blk, 0, stream>>>(ckv, kva_ln, kvn, 512, 576, 512);
    rope_k_kernel<<<4096, dim3(64), 0, stream>>>(ckv, cosb, sinb, kpe);

    // G3: qbuf = q_a_norm @ w_qb (pre-scaled); then rope (PE dims only)
    gemm_tt<unsigned short><<<dim3(24, 32), blk, 0, stream>>>(
        q_a, qbt, qbuf, qbuf, 1536, 3072, 3072, 3072, 3072);
    rope_q_kernel<<<4096, blk, 0, stream>>>(qbuf, cosb, sinb);

    // G4: [Kn | VT] = kv_norm @ w_kvb  (split epilogue, coalesced VT)
    gemm_kv<<<dim3(32, 32), blk, 0, stream>>>(kvn, kvbt, Kn, VT, 512);

    // attention: flat grid, XCD-co-located (h,b) groups, paired q-tiles
    flash_kernel<<<dim3(512), blk, 0, stream>>>(qbuf, Kn, kpe, VT, aout);

    // w_o transpose (deferred: reuses VT region after flash)
    wtrans_kernel<<<dim3(32, 32), blk, 0, stream>>>(w_o, ot, 2048, 2048, 0, 1.0f);

    // G5: out = attn_out @ w_o (fp32 output)
    gemm_tt<float><<<dim3(16, 32), blk, 0, stream>>>(
        aout, ot, out, out, 2048, 2048, 2048, 2048, 2048);
}